// Round 2
// baseline (208.138 us; speedup 1.0000x reference)
//
#include <hip/hip_runtime.h>

// RandomShiftsAug: out[n,c,h,w] = x[n,c, clamp(h+sy,0,83), clamp(w+sx,0,83)],
// sx,sy = shift[n] - 4 in [-4,4], uniform per image (shared by all 4 channels).
// Reference's bilinear coords are exactly integer -> pure edge-clamped gather.
//
// R5 (retry; previous submit died to container-infra failure, no kernel verdict).
//   Evidence: harness fills hit 6.8 TB/s; R4 kernel residual ~59us vs ~36us
//   copy floor. R4 was MLP=1 (load -> block barrier -> consume -> store) and
//   its 4 clamped stride-4 ds_read_b32 put all 63 lanes of a wave into one
//   mod-4 bank class (~8-way conflict, m136 ~2.9x). 28672 tiny 252-thr blocks.
//   R5:
//   - plane-per-block: 4096 blocks x 256 thr; block b streams plane b
//     contiguously (in b*28KB, out b*28KB).
//   - wave-owned rows: 21 lanes x 3 rows per wave, lane 63 idle. Producer
//     lanes == consumer wave -> NO __syncthreads (DS ops in-order per wave;
//     wave_barrier pins write->read scheduling). No cross-wave coupling.
//   - 7-band loop, 1-deep global prefetch: 2 float4 loads in flight/thread,
//     stores overlap next band's loads (compiler emits counted vmcnt).
//   - LDS rows padded 4+84+4 with edge-replicated values: column clamp free.
//   - column shift via aligned b128 reads + uniform (SGPR) sub-word select:
//     shift is per-image uniform -> scalar branch, no divergence, ~0 bank
//     conflicts (b128 at word-stride-1), no per-element min/max chain.
//   LDS-OOB audit: q==2 only when s4==8 (r==0); the +1 read occurs only when
//   r!=0 (q<=1) -> max word idx 22 (floats 88..91 < 92). Writes max word 91.
// Predicted: kernel ~40us @ ~5.5 TB/s, SQ_LDS_BANK_CONFLICT ~0,
// bench dur_us 195.7 -> ~176.

#define HW 84
#define PADV 4
#define PLANE (HW * HW)       // 7056 floats per (n,c) plane
#define LROW 92               // padded LDS row: 4 + 84 + 4 floats (368B, 16B-aligned)
#define BANDS 7               // 84 rows = 7 bands x (4 waves x 3 rows)

__global__ __launch_bounds__(256)
void shift_aug_kernel(const float* __restrict__ x,
                      const int* __restrict__ shift,
                      float* __restrict__ out) {
    __shared__ float lds[4][2][3][LROW];   // [wave][buf][row-in-trio][padded cols]

    const int lane = threadIdx.x;          // 0..63
    const int w    = threadIdx.y;          // 0..3 (wave id)
    const int b    = blockIdx.x;           // 0..4095 == n*4 + c, planes are linear

    const int n  = b >> 2;
    const int sx = shift[2 * n]     - PADV;   // uniform -> SGPR
    const int sy = shift[2 * n + 1] - PADV;
    const int s4 = sx + PADV;              // [0,8]
    const int q  = s4 >> 2;                // word shift 0..2   (SGPR)
    const int r  = s4 & 3;                 // sub-word shift 0..3 (SGPR)

    const int j  = lane / 21;              // row within wave's trio (3 == idle lane)
    const int tx = lane - j * 21;          // float4 index within row [0,21)
    const bool active = (lane < 63);

    const float* __restrict__ plane  = x   + (size_t)b * PLANE;
    float*       __restrict__ oplane = out + (size_t)b * PLANE;

    const int rbase = w * 3 + j;           // row within band [0,12)

    // prefetch band 0
    float4 L = make_float4(0.f, 0.f, 0.f, 0.f);
    {
        const int sh = min(max(rbase + sy, 0), HW - 1);
        if (active) L = ((const float4*)(plane + sh * HW))[tx];
    }

    #pragma unroll
    for (int t = 0; t < BANDS; ++t) {
        // issue next band's load before consuming current (keeps 2 in flight)
        float4 Ln = L;
        if (t + 1 < BANDS) {
            const int sh1 = min(max((t + 1) * 12 + rbase + sy, 0), HW - 1);
            if (active) Ln = ((const float4*)(plane + sh1 * HW))[tx];
        }

        float* row = &lds[w][t & 1][j][0];
        if (active) {
            ((float4*)row)[1 + tx] = L;                               // words 1..21 = cols 0..83
            if (tx == 0)  ((float4*)row)[0]  = make_float4(L.x, L.x, L.x, L.x); // left pad = col0
            if (tx == 20) ((float4*)row)[22] = make_float4(L.w, L.w, L.w, L.w); // right pad = col83
        }
        __builtin_amdgcn_wave_barrier();   // intra-wave write->read order; no s_barrier

        if (active) {
            const float4* row4 = (const float4*)row;
            // padded source base = 4*tx + s4; o[k] = paddedrow[4*tx + s4 + k]
            const float4 a = row4[tx + q];
            float4 o;
            if (r == 0) {                  // uniform SGPR branch, no divergence
                o = a;
            } else {
                const float4 bb = row4[tx + q + 1];
                if (r == 1)      o = make_float4(a.y, a.z, a.w, bb.x);
                else if (r == 2) o = make_float4(a.z, a.w, bb.x, bb.y);
                else             o = make_float4(a.w, bb.x, bb.y, bb.z);
            }
            ((float4*)(oplane + (t * 12 + rbase) * HW))[tx] = o;
        }
        L = Ln;
    }
}

extern "C" void kernel_launch(void* const* d_in, const int* in_sizes, int n_in,
                              void* d_out, int out_size, void* d_ws, size_t ws_size,
                              hipStream_t stream) {
    const float* x     = (const float*)d_in[0];
    const int*   shift = (const int*)d_in[1];
    float*       out   = (float*)d_out;

    dim3 block(64, 4, 1);      // 4 full waves; each wave owns 3 rows x 21 lanes
    dim3 grid(4096, 1, 1);     // one (n,c) plane per block, linear in memory
    shift_aug_kernel<<<grid, block, 0, stream>>>(x, shift, out);
}

// Round 3
// 200.656 us; speedup vs baseline: 1.0373x; 1.0373x over previous
//
#include <hip/hip_runtime.h>

// RandomShiftsAug: out[n,c,h,w] = x[n,c, clamp(h+sy,0,83), clamp(w+sx,0,83)],
// sx,sy = shift[n] - 4 in [-4,4], uniform per image. Pure edge-clamped gather.
//
// R5 -> R6: kill LDS entirely; go deep-MLP pure streaming.
//   Post-mortem R5: predicted ~0 bank conflicts, got 3.36M; kernel 59->71us,
//   HBM 2.4 TB/s, VALUBusy 8%, occ 63%. FIVE structures (branchy / vector /
//   misaligned / LDS+barrier / wave-autonomous LDS) all land 59-73us at
//   2.3-3.2 TB/s combined, while fills hit 6.8 and m13 float4 COPY (same
//   read+write mix) hits 6.3. Common defect: per-thread MLP <= 2, serialized
//   against DS round-trips / barriers. Little's law: ~9KB outstanding loads
//   per CU needed for 6.3 TB/s; MLP<=2 structures sustain ~4 wave-loads/CU
//   -> exactly the measured ~2.4 TB/s.
//   R6 = the copy-kernel shape, adapted to a shifted gather:
//   - no LDS, no barriers, no exec-masked main path;
//   - plane-per-block, 256 thr x 7 float4; all 7 loads issued before any
//     use (independent -> counted vmcnt, 7KB in flight per wave);
//   - column shift in registers: one unaligned (4B-aligned) float4 load at
//     clamped base B=clamp(4tx+sx,0,80), then uniform per-element select
//     o[k] = L[clamp(k+d,0,3)], d = 4tx+sx-B (0 for interior lanes, handles
//     both edges; verified for all sx in [-4,4], tx in {0,20}).
// Predicted: kernel ~40us @ ~4.2 TB/s dispatch HBM, LDS conflicts 0,
// VALUBusy ~30%, bench ~175us.

#define HW 84
#define PADV 4
#define PLANE (HW * HW)      // 7056 floats per (n,c) plane
#define PF4   (PLANE / 4)    // 1764 float4 per plane
#define NTHR  256
#define K     7              // ceil(1764/256): float4s per thread

// 4-byte-aligned float4: gfx9+ global_load_dwordx4 only needs dword alignment.
struct __attribute__((aligned(4))) f4u { float x, y, z, w; };

__device__ __forceinline__ float pick(const f4u& v, int idx) {
    // idx in [0,3] -> 3 cndmask chain, branchless
    return (idx < 1) ? v.x : (idx < 2) ? v.y : (idx < 3) ? v.z : v.w;
}

__global__ __launch_bounds__(NTHR)
void shift_aug_kernel(const float* __restrict__ x,
                      const int* __restrict__ shift,
                      float* __restrict__ out) {
    const int tid = threadIdx.x;
    const int b   = blockIdx.x;        // plane id = n*4 + c (planes linear)
    const int n   = b >> 2;

    const int sx = shift[2 * n]     - PADV;   // uniform -> SGPR
    const int sy = shift[2 * n + 1] - PADV;

    const float* __restrict__ plane  = x   + (size_t)b * PLANE;
    float*       __restrict__ oplane = out + (size_t)b * PLANE;

    int src[K];    // source float-offset within plane (4B-aligned load base)
    int dsel[K];   // per-element select correction, 0 for interior lanes

    #pragma unroll
    for (int i = 0; i < K; ++i) {
        const int g   = tid + NTHR * i;             // output float4 index
        const int gi  = (g < PF4) ? g : (PF4 - 1);  // clamp tail (load only)
        const int row = gi / 21;                    // compiler magic-mul
        const int tx  = gi - row * 21;
        const int srow = min(max(row + sy, 0), HW - 1);
        const int cb   = 4 * tx + sx;               // wanted start col, may be OOB
        const int B    = min(max(cb, 0), HW - 4);   // clamped 4-valid load base
        src[i]  = srow * HW + B;
        dsel[i] = cb - B;                           // in [-4,4]; 0 unless edge lane
    }

    // Issue all 7 independent loads back-to-back: deep MLP, counted vmcnt.
    f4u L[K];
    #pragma unroll
    for (int i = 0; i < K; ++i)
        L[i] = *(const f4u*)(plane + src[i]);

    #pragma unroll
    for (int i = 0; i < K; ++i) {
        const int d = dsel[i];
        float4 o;
        o.x = pick(L[i], min(max(d,     0), 3));
        o.y = pick(L[i], min(max(d + 1, 0), 3));
        o.z = pick(L[i], min(max(d + 2, 0), 3));
        o.w = pick(L[i], min(max(d + 3, 0), 3));
        const int g = tid + NTHR * i;
        if (i < K - 1) {
            ((float4*)oplane)[g] = o;               // g < 1536 < PF4 always
        } else if (g < PF4) {
            ((float4*)oplane)[g] = o;               // masked tail (228/256 active)
        }
    }
}

extern "C" void kernel_launch(void* const* d_in, const int* in_sizes, int n_in,
                              void* d_out, int out_size, void* d_ws, size_t ws_size,
                              hipStream_t stream) {
    const float* x     = (const float*)d_in[0];
    const int*   shift = (const int*)d_in[1];
    float*       out   = (float*)d_out;

    dim3 block(NTHR, 1, 1);
    dim3 grid(4096, 1, 1);     // one (n,c) plane per block, linear in memory
    shift_aug_kernel<<<grid, block, 0, stream>>>(x, shift, out);
}